// Round 10
// baseline (1123.282 us; speedup 1.0000x reference)
//
#include <hip/hip_runtime.h>

typedef unsigned short u16;
typedef unsigned int   u32;
typedef __attribute__((ext_vector_type(8))) short short8;
typedef __attribute__((ext_vector_type(4))) float f32x4;

#define HW_   16384
constexpr long CHW_ = 4194304L;
constexpr long NT   = 33554432L; // B*C*H*W

#define GLDS(g, l) __builtin_amdgcn_global_load_lds( \
    (const __attribute__((address_space(1))) void*)(g), \
    (__attribute__((address_space(3))) void*)(l), 16, 0, 0)

__device__ inline u16 f2bf(float x){ u32 u = __float_as_uint(x); u += 0x7fff + ((u>>16)&1); return (u16)(u>>16); }
__device__ inline float bf2f(u16 h){ return __uint_as_float(((u32)h)<<16); }

// tile rows: 128 B (8 chunks of 16 B), source-side swizzle XOR (r&7)
__device__ inline const short8* frg(const u16* T, int r, int c){
  return (const short8*)(T + r*64 + ((c ^ (r&7))<<3));
}

// Split layout (X/Q/K/Wcat): row = 512 u16 = 8 blocks of [32 hi | 32 lo] (1024 B), BK=32/step.
// Plain layout (Mt/V/att/Wv): row = K-contiguous bf16, BK=64/step.
// Every K-step stages 128 B per row per tensor.
//
// m97-style loop: single 32 KB buffer, stage -> __syncthreads (vmcnt0 drain) ->
// frags+MFMA -> __syncthreads. Latency hidden by 4 blocks/CU (TLP), not prefetch.
//
// MODE 0: proj q+k fused (split A=Xs, B=Wcat; interleaved split out -> Qs/Ks)
// MODE 1: energy both dirs (split; fp32 out att slice; dir from blockIdx)
// MODE 2: proj v (plain; bias by row; bf16 out [b][c][p])
// MODE 3: av fused H+W (plain; blockIdx.z picks (Vtb,aHb,tmp) vs (Vb,aWb,pW))
template<int MODE>
__global__ __launch_bounds__(256, 4) void gemm_nt(
    const char* __restrict__ Aq, const char* __restrict__ Bq,
    const char* __restrict__ Aq2, const char* __restrict__ Bq2,
    const float* __restrict__ bias, const float* __restrict__ gammap,
    float* __restrict__ outFa, float* __restrict__ outFb,
    u16* __restrict__ outUa, u16* __restrict__ outUb)
{
  constexpr bool SP  = (MODE <= 1);
  constexpr int  NTl = SP ? 8 : (MODE == 2 ? 4 : 2);
  // stage area 16384 u16 (A 16 KB + B 16 KB); epilogue fp32 [64][132] = 16896 u16
  __shared__ __align__(16) u16 smem[16896];

  const int t    = threadIdx.x;
  const int lane = t & 63;
  const int wid  = t >> 6;
  const int wr   = (wid >> 1) << 6;
  const int wc   = (wid & 1) << 6;

  long abase = 0, bbase = 0, ars = 0, brs = 0;
  int b = 0, m0 = 0, n0 = 0, xx = 0, ct = 0, dir = 0, sOut = 0;
  const char* Ause = Aq;
  const char* Buse = Bq;
  u16* outU = outUa;

  if constexpr (MODE == 0) {
    int bid = blockIdx.x;                     // 4096, XCD-chunked (bijective: 4096%8==0)
    int orig = (bid & 7) * 512 + (bid >> 3);
    b = orig >> 9; m0 = ((orig >> 2) & 127) << 7; n0 = (orig & 3) << 7;
    abase = ((long)b * HW_ + m0) * 1024; ars = 1024;
    bbase = (long)n0 * 1024;             brs = 1024;
  } else if constexpr (MODE == 1) {
    int bid = blockIdx.x;                     // 2048, natural order
    b = bid >> 8; dir = (bid >> 7) & 1; xx = bid & 127;
    sOut = b * 128 + xx;
    if (dir) { abase = (long)b * 16777216L + (long)xx * 1024; ars = 131072; }
    else     { abase = (long)b * 16777216L + (long)xx * 131072; ars = 1024; }
    bbase = abase; brs = ars;
  } else if constexpr (MODE == 2) {
    b = blockIdx.z; m0 = blockIdx.y << 7; n0 = blockIdx.x << 7;
    abase = (long)m0 * 512;              ars = 512;
    bbase = ((long)b * HW_ + n0) * 512;  brs = 512;
  } else {
    int s = blockIdx.x; ct = blockIdx.y; b = s >> 7; xx = s & 127;
    sOut = s;
    if (blockIdx.z) { Ause = Aq2; Buse = Bq2; outU = outUb; }
    abase = ((long)b * 256 + (long)(ct << 7)) * 32768L + (long)xx * 256; ars = 32768;
    bbase = (long)s * 32768L; brs = 256;
  }

  const char* pA = Ause + abase;
  const char* pB = Buse + bbase;

  f32x4 acc[4][4];
  for (int i = 0; i < 4; i++)
    for (int j = 0; j < 4; j++)
      acc[i][j] = (f32x4){0.f, 0.f, 0.f, 0.f};

  const int khi = lane >> 4;
  const int rl  = lane & 15;

  #pragma unroll
  for (int kt = 0; kt < NTl; ++kt) {
    // stage K-step kt (source-side swizzle, linear GLDS dest)
    {
      const long ko = (long)kt * 128;
      #pragma unroll
      for (int i = 0; i < 4; i++) {
        int r = (i << 5) + (t >> 3);
        int c = (t & 7) ^ (r & 7);
        GLDS(pA + (long)r * ars + ko + (c << 4), smem + (i << 11) + ((t >> 6) << 9));
        GLDS(pB + (long)r * brs + ko + (c << 4), smem + 8192 + (i << 11) + ((t >> 6) << 9));
      }
    }
    __syncthreads();   // compiler emits vmcnt(0) drain; cross-block TLP hides it

    const u16* T1 = smem;
    const u16* T2 = smem + 8192;

    if constexpr (SP) {
      short8 fa0[4], fa1[4], fb0[4], fb1[4];
      #pragma unroll
      for (int f = 0; f < 4; f++) {
        fa0[f] = *frg(T1, wr + f * 16 + rl, khi);
        fa1[f] = *frg(T1, wr + f * 16 + rl, 4 + khi);
        fb0[f] = *frg(T2, wc + f * 16 + rl, khi);
        fb1[f] = *frg(T2, wc + f * 16 + rl, 4 + khi);
      }
      __builtin_amdgcn_s_setprio(1);
      #pragma unroll
      for (int fm = 0; fm < 4; fm++) {
        #pragma unroll
        for (int fn = 0; fn < 4; fn++) {
          // split: hi*hi + hi*lo + lo*hi
          acc[fm][fn] = __builtin_amdgcn_mfma_f32_16x16x32_bf16(fa0[fm], fb0[fn], acc[fm][fn], 0, 0, 0);
          acc[fm][fn] = __builtin_amdgcn_mfma_f32_16x16x32_bf16(fa0[fm], fb1[fn], acc[fm][fn], 0, 0, 0);
          acc[fm][fn] = __builtin_amdgcn_mfma_f32_16x16x32_bf16(fa1[fm], fb0[fn], acc[fm][fn], 0, 0, 0);
        }
      }
      __builtin_amdgcn_s_setprio(0);
    } else {
      short8 fa0[4], fa1[4], fb0[4], fb1[4];
      #pragma unroll
      for (int f = 0; f < 4; f++) {
        fa0[f] = *frg(T1, wr + f * 16 + rl, khi);       // k 0..31
        fa1[f] = *frg(T1, wr + f * 16 + rl, 4 + khi);   // k 32..63
        fb0[f] = *frg(T2, wc + f * 16 + rl, khi);
        fb1[f] = *frg(T2, wc + f * 16 + rl, 4 + khi);
      }
      __builtin_amdgcn_s_setprio(1);
      #pragma unroll
      for (int fm = 0; fm < 4; fm++) {
        #pragma unroll
        for (int fn = 0; fn < 4; fn++) {
          acc[fm][fn] = __builtin_amdgcn_mfma_f32_16x16x32_bf16(fa0[fm], fb0[fn], acc[fm][fn], 0, 0, 0);
          acc[fm][fn] = __builtin_amdgcn_mfma_f32_16x16x32_bf16(fa1[fm], fb1[fn], acc[fm][fn], 0, 0, 0);
        }
      }
      __builtin_amdgcn_s_setprio(0);
    }

    __syncthreads();   // all waves done reading -> buffer reusable next step
  }

  // ---------- 2-pass epilogue: fragments -> LDS fp32 [64][132] -> wide stores ----------
  float gma = 0.f;
  if constexpr (MODE == 3) gma = gammap[0];
  float* LDSE = (float*)smem;

  #pragma unroll
  for (int pass = 0; pass < 2; ++pass) {
    if (pass) __syncthreads();
    if ((wid >> 1) == pass) {
      #pragma unroll
      for (int fm = 0; fm < 4; fm++) {
        #pragma unroll
        for (int fn = 0; fn < 4; fn++) {
          #pragma unroll
          for (int r = 0; r < 4; r++) {
            int Lr = fm * 16 + ((lane >> 4) << 2) + r;   // 0..63
            int lc = wc + fn * 16 + rl;                  // 0..127
            float v = acc[fm][fn][r];
            if constexpr (MODE == 0) v += bias[n0 + lc];
            if constexpr (MODE == 2) v += bias[m0 + pass * 64 + Lr];
            if constexpr (MODE == 3) v *= gma;
            LDSE[Lr * 132 + lc] = v;
          }
        }
      }
    }
    __syncthreads();

    if constexpr (MODE == 0) {
      u16* outp = (n0 < 256) ? outUa : outUb;
      long rowb = ((long)b * HW_ + m0) * 512;
      int cbu = (n0 & 255) * 2;
      #pragma unroll
      for (int k = 0; k < 8; ++k) {
        int Lr = k * 8 + (t >> 5);
        int row = pass * 64 + Lr;
        int iu  = (t & 31) * 8;
        int off = iu & 63;
        int lcol = (iu >> 6) * 32 + (off & 31);
        const float* src = &LDSE[Lr * 132 + lcol];
        u16 o[8];
        if (off < 32) {
          #pragma unroll
          for (int j = 0; j < 8; j++) o[j] = f2bf(src[j]);
        } else {
          #pragma unroll
          for (int j = 0; j < 8; j++) { float v = src[j]; u16 h = f2bf(v); o[j] = f2bf(v - bf2f(h)); }
        }
        *(short8*)(outp + rowb + (long)row * 512 + cbu + iu) = *(short8*)o;
      }
    } else if constexpr (MODE == 1) {
      float* op = dir ? outFb : outFa;
      long ob = (long)sOut * 16384;
      #pragma unroll
      for (int k = 0; k < 8; ++k) {
        int Lr = k * 8 + (t >> 5);
        int row = pass * 64 + Lr;
        int c4 = (t & 31) * 4;
        f32x4 v = *(const f32x4*)&LDSE[Lr * 132 + c4];
        *(f32x4*)(op + ob + (long)row * 128 + c4) = v;
      }
    } else {
      #pragma unroll
      for (int k = 0; k < 4; ++k) {
        int Lr = k * 16 + (t >> 4);
        int row = pass * 64 + Lr;
        int c8 = (t & 15) * 8;
        const float* src = &LDSE[Lr * 132 + c8];
        u16 o[8];
        #pragma unroll
        for (int j = 0; j < 8; j++) o[j] = f2bf(src[j]);
        long addr;
        if constexpr (MODE == 2) addr = ((long)b * 256 + m0 + row) * HW_ + n0 + c8;
        else                     addr = ((long)b * 256 + (ct << 7) + row) * HW_ + (long)xx * 128 + c8;
        *(short8*)(outU + addr) = *(short8*)o;
      }
    }
  }
}

// ---------------- fused: edge -> interleaved split bf16 [p][c], mask -> plain bf16 [p][c] ----
__global__ __launch_bounds__(256) void split_transpose2(const float* __restrict__ edge,
    const float* __restrict__ mask, u16* __restrict__ Xs, u16* __restrict__ Mt)
{
  int b = blockIdx.z, c0 = blockIdx.y << 5, p0 = blockIdx.x << 5;
  __shared__ float tileE[32][33];
  __shared__ float tileM[32][33];
  int tx = threadIdx.x, ty = threadIdx.y;
  const float* E = edge + (long)b * CHW_;
  const float* M = mask + (long)b * CHW_;
  #pragma unroll
  for (int r = 0; r < 4; r++) {
    int cc = ty + (r << 3);
    long g = (long)(c0 + cc) * HW_ + p0 + tx;
    tileE[cc][tx] = E[g];
    tileM[cc][tx] = M[g];
  }
  __syncthreads();
  int blk = (c0 >> 5) * 64;
  #pragma unroll
  for (int r = 0; r < 4; r++) {
    int pp = ty + (r << 3);
    long prow = (long)b * HW_ + p0 + pp;
    float x = tileE[tx][pp];
    u16 h = f2bf(x);
    Xs[prow * 512 + blk + tx]      = h;
    Xs[prow * 512 + blk + 32 + tx] = f2bf(x - bf2f(h));
    Mt[prow * 256 + c0 + tx]       = f2bf(tileM[tx][pp]);
  }
}

// ---------------- weight prep: Wcat=[Wq;Wk] interleaved split, Wv plain, bias cat ----------
__global__ __launch_bounds__(256) void wsplit(const float* __restrict__ Wq,
    const float* __restrict__ Wk, const float* __restrict__ Wv,
    const float* __restrict__ bq, const float* __restrict__ bk,
    u16* Wc, u16* Wvp, float* bcat)
{
  int i = blockIdx.x * 256 + threadIdx.x;
  int o = i >> 8, c = i & 255;
  long pos = (long)o * 512 + (c >> 5) * 64 + (c & 31);
  float q = Wq[i]; u16 a = f2bf(q); Wc[pos] = a; Wc[pos + 32] = f2bf(q - bf2f(a));
  float k = Wk[i]; u16 d = f2bf(k);
  Wc[pos + 131072] = d; Wc[pos + 131072 + 32] = f2bf(k - bf2f(d));
  Wvp[i] = f2bf(Wv[i]);
  if (blockIdx.x == 0) {
    bcat[threadIdx.x]       = bq[threadIdx.x];
    bcat[256 + threadIdx.x] = bk[threadIdx.x];
  }
}

// ---------------- bf16 H<->W transpose: dst[bc][w*128+h] = src[bc][h*128+w] ----------------
__global__ __launch_bounds__(256) void transpose_hw_bf16(const u16* __restrict__ src,
                                                         u16* __restrict__ dst)
{
  int bc = blockIdx.z;
  int h0 = blockIdx.x << 5, w0 = blockIdx.y << 5;
  long base = (long)bc * HW_;
  __shared__ u16 tile[32][34];
  int tx = threadIdx.x, ty = threadIdx.y;
  #pragma unroll
  for (int r = 0; r < 4; r++)
    tile[ty + (r << 3)][tx] = src[base + (long)(h0 + ty + (r << 3)) * 128 + w0 + tx];
  __syncthreads();
  #pragma unroll
  for (int r = 0; r < 4; r++) {
    int ww = ty + (r << 3);
    dst[base + (long)(w0 + ww) * 128 + h0 + tx] = tile[tx][ww];
  }
}

// ---------------- softmax over concat(rowH[128], rowW[128]) + bf16 copies, vectorized ------
__global__ __launch_bounds__(256) void softmax_kernel(float* __restrict__ attH,
    float* __restrict__ attW, u16* __restrict__ aHb, u16* __restrict__ aWb)
{
  int g  = threadIdx.x & 31;                     // 32 lanes per row
  long r = (long)blockIdx.x * 8 + (threadIdx.x >> 5);
  int b = (int)(r >> 14);
  int h = (int)((r >> 7) & 127);
  int w = (int)(r & 127);
  long baseH = ((long)(b * 128 + w) * 128 + h) * 128;
  long baseW = r * 128;
  float* rp = (g < 16) ? (attH + baseH) : (attW + baseW);
  u16*   up = (g < 16) ? (aHb + baseH)  : (aWb + baseW);
  int j0 = (g & 15) * 8;
  f32x4 v0 = *(f32x4*)(rp + j0);
  f32x4 v1 = *(f32x4*)(rp + j0 + 4);
  float m = fmaxf(fmaxf(fmaxf(v0.x, v0.y), fmaxf(v0.z, v0.w)),
                  fmaxf(fmaxf(v1.x, v1.y), fmaxf(v1.z, v1.w)));
  #pragma unroll
  for (int off = 16; off; off >>= 1) m = fmaxf(m, __shfl_xor(m, off, 32));
  float e[8];
  e[0]=expf(v0.x-m); e[1]=expf(v0.y-m); e[2]=expf(v0.z-m); e[3]=expf(v0.w-m);
  e[4]=expf(v1.x-m); e[5]=expf(v1.y-m); e[6]=expf(v1.z-m); e[7]=expf(v1.w-m);
  float s = ((e[0]+e[1])+(e[2]+e[3])) + ((e[4]+e[5])+(e[6]+e[7]));
  #pragma unroll
  for (int off = 16; off; off >>= 1) s += __shfl_xor(s, off, 32);
  float inv = 1.0f / s;
  #pragma unroll
  for (int j = 0; j < 8; j++) e[j] *= inv;
  __builtin_nontemporal_store((f32x4){e[0], e[1], e[2], e[3]}, (f32x4*)(rp + j0));
  __builtin_nontemporal_store((f32x4){e[4], e[5], e[6], e[7]}, (f32x4*)(rp + j0 + 4));
  u16 o[8];
  #pragma unroll
  for (int j = 0; j < 8; j++) o[j] = f2bf(e[j]);
  *(short8*)(up + j0) = *(short8*)o;
}

// ---------------- merge: out = pW + tmp^T + mask ----------------
__global__ __launch_bounds__(256) void merge_kernel(const u16* __restrict__ tmp,
    const u16* __restrict__ pW, const float* __restrict__ mask, float* __restrict__ out)
{
  int bc = blockIdx.z;
  int h0 = blockIdx.x << 5, w0 = blockIdx.y << 5;
  long base = (long)bc * HW_;
  __shared__ u16 tile[32][33];
  int tx = threadIdx.x, ty = threadIdx.y;
  #pragma unroll
  for (int r = 0; r < 4; r++) {
    int ww = ty + (r << 3);
    tile[ww][tx] = tmp[base + (long)(w0 + ww) * 128 + h0 + tx];
  }
  __syncthreads();
  #pragma unroll
  for (int r = 0; r < 4; r++) {
    int hh = ty + (r << 3);
    long o = base + (long)(h0 + hh) * 128 + w0 + tx;
    float v = bf2f(pW[o]) + bf2f(tile[tx][hh]) + mask[o];
    __builtin_nontemporal_store(v, out + o);
  }
}

extern "C" void kernel_launch(void* const* d_in, const int* in_sizes, int n_in,
                              void* d_out, int out_size, void* d_ws, size_t ws_size,
                              hipStream_t stream) {
  const float* edge  = (const float*)d_in[0];
  const float* mask  = (const float*)d_in[1];
  const float* Wq    = (const float*)d_in[2];
  const float* bq    = (const float*)d_in[3];
  const float* Wk    = (const float*)d_in[4];
  const float* bk    = (const float*)d_in[5];
  const float* Wv    = (const float*)d_in[6];
  const float* bv    = (const float*)d_in[7];
  const float* gamma = (const float*)d_in[8];

  float* out  = (float*)d_out;
  float* attH = out + NT;            // B*W*H*H
  float* attW = attH + 16777216L;    // B*H*W*W

  char* W = (char*)d_ws;
  u16* Xs  = (u16*)(W);                    // 128 MiB interleaved split X [b][p][512]
  u16* Mt  = (u16*)(W + 134217728L);       // 64 MiB plain bf16 mask^T [b][p][256]
  u16* Qs  = (u16*)(W + 201326592L);       // 128 MiB
  u16* Ks  = (u16*)(W + 335544320L);       // 128 MiB
  u16* Vb  = (u16*)(W + 469762048L);       // 64 MiB
  u16* Wc  = (u16*)(W + 536870912L);       // 512 KiB Wcat interleaved
  u16* Wvp = Wc + 262144;                  // 128 KiB
  float* bcat = (float*)(Wvp + 65536);
  // reuses
  u16* Vtb = (u16*)(W);                    // over Xs (dead after proj qk)
  u16* aWb = (u16*)(W + 67108864L);        // over Xs upper half
  u16* aHb = (u16*)(W + 100663296L);
  u16* tmp = (u16*)(W + 201326592L);       // over Qs (dead after energy)
  u16* pW  = (u16*)(W + 335544320L);       // over Ks

  dim3 tb(32, 8);

  wsplit<<<256, 256, 0, stream>>>(Wq, Wk, Wv, bq, bk, Wc, Wvp, bcat);
  split_transpose2<<<dim3(512, 8, 8), tb, 0, stream>>>(edge, mask, Xs, Mt);

  gemm_nt<0><<<4096, 256, 0, stream>>>(
      (const char*)Xs, (const char*)Wc, nullptr, nullptr, bcat, nullptr,
      nullptr, nullptr, Qs, Ks);
  gemm_nt<2><<<dim3(128, 2, 8), 256, 0, stream>>>(
      (const char*)Wvp, (const char*)Mt, nullptr, nullptr, bv, nullptr,
      nullptr, nullptr, Vb, nullptr);

  transpose_hw_bf16<<<dim3(4, 4, 2048), tb, 0, stream>>>(Vb, Vtb);

  gemm_nt<1><<<2048, 256, 0, stream>>>(
      (const char*)Qs, (const char*)Ks, nullptr, nullptr, nullptr, nullptr,
      attW, attH, nullptr, nullptr);

  softmax_kernel<<<16384, 256, 0, stream>>>(attH, attW, aHb, aWb);

  // fused av: z=0 -> H-direction (Vtb x aHb -> tmp), z=1 -> W-direction (Vb x aWb -> pW)
  gemm_nt<3><<<dim3(1024, 2, 2), 256, 0, stream>>>(
      (const char*)Vtb, (const char*)aHb, (const char*)Vb, (const char*)aWb,
      nullptr, gamma, nullptr, nullptr, tmp, pW);

  merge_kernel<<<dim3(4, 4, 2048), tb, 0, stream>>>(tmp, pW, mask, out);
}

// Round 12
// 671.050 us; speedup vs baseline: 1.6739x; 1.6739x over previous
//
#include <hip/hip_runtime.h>

typedef unsigned short u16;
typedef unsigned int   u32;
typedef __attribute__((ext_vector_type(8))) short short8;
typedef __attribute__((ext_vector_type(4))) float f32x4;

#define HW_   16384
constexpr long CHW_ = 4194304L;
constexpr long NT   = 33554432L; // B*C*H*W

#define GLDS(g, l) __builtin_amdgcn_global_load_lds( \
    (const __attribute__((address_space(1))) void*)(g), \
    (__attribute__((address_space(3))) void*)(l), 16, 0, 0)

__device__ inline u16 f2bf(float x){ u32 u = __float_as_uint(x); u += 0x7fff + ((u>>16)&1); return (u16)(u>>16); }
__device__ inline float bf2f(u16 h){ return __uint_as_float(((u32)h)<<16); }

// swizzled LDS tile: 128 rows x 8 chunks of 16B. elem(row r, chunk c) at
// u16 index r*64 + ((c ^ (r&7))<<3).
__device__ inline const short8* frg(const u16* T, int r, int c){
  return (const short8*)(T + r*64 + ((c ^ (r&7))<<3));
}

// Split layout (X/Q/K/Wcat): row = 512 u16 = 8 blocks of [32 hi | 32 lo] (1024 B).
// Plain layout (Mt/V/att/Wv): row = K-contiguous bf16.

// MODE 0: proj q+k fused. A=Xs staged (ring-2, 16 KB/step); B=Wcat read as per-lane
//         16-B fragments straight from global (L2-resident, shared by all blocks).
// MODE 1: energy both dirs (both staged, ring-2 32 KB/step; fp32 out att slice)
// MODE 2: proj v. B=Mt staged; A=Wv fragments from global.
// MODE 3: av fused H+W (both staged; blockIdx.z picks (Vtb,aHb,tmp) vs (Vb,aWb,pW))
template<int MODE>
__global__ __launch_bounds__(256, (MODE == 0 || MODE == 2) ? 3 : 1) void gemm_nt(
    const char* __restrict__ Aq, const char* __restrict__ Bq,
    const char* __restrict__ Aq2, const char* __restrict__ Bq2,
    const float* __restrict__ bias, const float* __restrict__ gammap,
    float* __restrict__ outFa, float* __restrict__ outFb,
    u16* __restrict__ outUa, u16* __restrict__ outUb)
{
  constexpr int  NTl   = (MODE == 3) ? 2 : (MODE == 2 ? 4 : 8);
  constexpr bool BGLOB = (MODE == 0);          // B fragments from global
  constexpr bool AGLOB = (MODE == 2);          // A fragments from global
  constexpr bool BOTH  = !(BGLOB || AGLOB);    // both operands LDS-staged
  constexpr int  SMEMU = BOTH ? 34048 : 16896; // u16
  __shared__ __align__(16) u16 smem[SMEMU];

  const int t    = threadIdx.x;
  const int lane = t & 63;
  const int wid  = t >> 6;
  const int wr   = (wid >> 1) << 6;
  const int wc   = (wid & 1) << 6;

  long abase = 0, bbase = 0, ars = 0, brs = 0;
  int b = 0, m0 = 0, n0 = 0, xx = 0, ct = 0, dir = 0, sOut = 0;
  const char* Ause = Aq;
  const char* Buse = Bq;
  u16* outU = outUa;

  if constexpr (MODE == 0) {
    b = blockIdx.z; m0 = blockIdx.x << 7; n0 = blockIdx.y << 7;
    abase = ((long)b * HW_ + m0) * 1024; ars = 1024;
    bbase = 0; brs = 0;
  } else if constexpr (MODE == 1) {
    int bid = blockIdx.x;
    b = bid >> 8; dir = (bid >> 7) & 1; xx = bid & 127;
    sOut = b * 128 + xx;
    if (dir) { abase = (long)b * 16777216L + (long)xx * 1024; ars = 131072; }
    else     { abase = (long)b * 16777216L + (long)xx * 131072; ars = 1024; }
    bbase = abase; brs = ars;
  } else if constexpr (MODE == 2) {
    b = blockIdx.z; m0 = blockIdx.y << 7; n0 = blockIdx.x << 7;
    abase = 0; ars = 0;
    bbase = ((long)b * HW_ + n0) * 512;  brs = 512;
  } else {
    int s = blockIdx.x; ct = blockIdx.y; b = s >> 7; xx = s & 127;
    sOut = s;
    if (blockIdx.z) { Ause = Aq2; Buse = Bq2; outU = outUb; }
    abase = ((long)b * 256 + (long)(ct << 7)) * 32768L + (long)xx * 256; ars = 32768;
    bbase = (long)s * 32768L; brs = 256;   // att row = 128 bf16 = 256 B (r11 bug: was 128)
  }

  const char* pA = Ause + abase;
  const char* pB = Buse + bbase;

  f32x4 acc[4][4];
  for (int i = 0; i < 4; i++)
    for (int j = 0; j < 4; j++)
      acc[i][j] = (f32x4){0.f, 0.f, 0.f, 0.f};

  // stage one K-step into ring buffer (source-side swizzle, linear GLDS dest)
  auto stage = [&](int buf, int kt) {
    const long ko = (long)kt * 128;
    u16* TS = BOTH ? (smem + buf * 17024) : (smem + buf * 8192);
    #pragma unroll
    for (int i = 0; i < 4; i++) {
      int r = (i << 5) + (t >> 3);
      int c = (t & 7) ^ (r & 7);
      if constexpr (!AGLOB)
        GLDS(pA + (long)r * ars + ko + (c << 4), TS + (i << 11) + ((t >> 6) << 9));
      if constexpr (!BGLOB) {
        u16* TB = BOTH ? (TS + 8192) : TS;
        GLDS(pB + (long)r * brs + ko + (c << 4), TB + (i << 11) + ((t >> 6) << 9));
      }
    }
  };

  const int khi = lane >> 4;
  const int rl  = lane & 15;

  stage(0, 0);
  stage(1, 1);

  #pragma unroll
  for (int kt = 0; kt < NTl; ++kt) {
    if (kt + 1 < NTl) {
      if constexpr (BOTH) asm volatile("s_waitcnt vmcnt(8)" ::: "memory");
      else                asm volatile("s_waitcnt vmcnt(4)" ::: "memory");
    } else {
      asm volatile("s_waitcnt vmcnt(0)" ::: "memory");
    }
    __builtin_amdgcn_sched_barrier(0);
    __builtin_amdgcn_s_barrier();
    __builtin_amdgcn_sched_barrier(0);

    if constexpr (MODE == 0) {
      const u16* T1 = smem + (kt & 1) * 8192;
      short8 fa0[4], fa1[4], fb0[4], fb1[4];
      #pragma unroll
      for (int f = 0; f < 4; f++) {
        fa0[f] = *frg(T1, wr + f * 16 + rl, khi);
        fa1[f] = *frg(T1, wr + f * 16 + rl, 4 + khi);
        const u16* rp = (const u16*)Bq + (long)(n0 + wc + f * 16 + rl) * 512 + kt * 64 + khi * 8;
        fb0[f] = *(const short8*)rp;          // hi chunk
        fb1[f] = *(const short8*)(rp + 32);   // lo chunk
      }
      __builtin_amdgcn_s_setprio(1);
      #pragma unroll
      for (int fm = 0; fm < 4; fm++) {
        #pragma unroll
        for (int fn = 0; fn < 4; fn++) {
          acc[fm][fn] = __builtin_amdgcn_mfma_f32_16x16x32_bf16(fa0[fm], fb0[fn], acc[fm][fn], 0, 0, 0);
          acc[fm][fn] = __builtin_amdgcn_mfma_f32_16x16x32_bf16(fa0[fm], fb1[fn], acc[fm][fn], 0, 0, 0);
          acc[fm][fn] = __builtin_amdgcn_mfma_f32_16x16x32_bf16(fa1[fm], fb0[fn], acc[fm][fn], 0, 0, 0);
        }
      }
      __builtin_amdgcn_s_setprio(0);
    } else if constexpr (MODE == 1) {
      const u16* T1 = smem + (kt & 1) * 17024;
      const u16* T2 = T1 + 8192;
      short8 fa0[4], fa1[4], fb0[4], fb1[4];
      #pragma unroll
      for (int f = 0; f < 4; f++) {
        fa0[f] = *frg(T1, wr + f * 16 + rl, khi);
        fa1[f] = *frg(T1, wr + f * 16 + rl, 4 + khi);
        fb0[f] = *frg(T2, wc + f * 16 + rl, khi);
        fb1[f] = *frg(T2, wc + f * 16 + rl, 4 + khi);
      }
      __builtin_amdgcn_s_setprio(1);
      #pragma unroll
      for (int fm = 0; fm < 4; fm++) {
        #pragma unroll
        for (int fn = 0; fn < 4; fn++) {
          acc[fm][fn] = __builtin_amdgcn_mfma_f32_16x16x32_bf16(fa0[fm], fb0[fn], acc[fm][fn], 0, 0, 0);
          acc[fm][fn] = __builtin_amdgcn_mfma_f32_16x16x32_bf16(fa0[fm], fb1[fn], acc[fm][fn], 0, 0, 0);
          acc[fm][fn] = __builtin_amdgcn_mfma_f32_16x16x32_bf16(fa1[fm], fb0[fn], acc[fm][fn], 0, 0, 0);
        }
      }
      __builtin_amdgcn_s_setprio(0);
    } else if constexpr (MODE == 2) {
      const u16* T2 = smem + (kt & 1) * 8192;
      short8 fa0[4], fa1[4], fb0[4], fb1[4];
      #pragma unroll
      for (int f = 0; f < 4; f++) {
        fb0[f] = *frg(T2, wc + f * 16 + rl, khi);
        fb1[f] = *frg(T2, wc + f * 16 + rl, 4 + khi);
        const u16* rp = (const u16*)Aq + (long)(m0 + wr + f * 16 + rl) * 256 + kt * 64 + khi * 8;
        fa0[f] = *(const short8*)rp;          // k 0..31 chunk
        fa1[f] = *(const short8*)(rp + 32);   // k 32..63 chunk
      }
      __builtin_amdgcn_s_setprio(1);
      #pragma unroll
      for (int fm = 0; fm < 4; fm++) {
        #pragma unroll
        for (int fn = 0; fn < 4; fn++) {
          acc[fm][fn] = __builtin_amdgcn_mfma_f32_16x16x32_bf16(fa0[fm], fb0[fn], acc[fm][fn], 0, 0, 0);
          acc[fm][fn] = __builtin_amdgcn_mfma_f32_16x16x32_bf16(fa1[fm], fb1[fn], acc[fm][fn], 0, 0, 0);
        }
      }
      __builtin_amdgcn_s_setprio(0);
    } else {
      const u16* T1 = smem + (kt & 1) * 17024;
      const u16* T2 = T1 + 8192;
      short8 fa0[4], fa1[4], fb0[4], fb1[4];
      #pragma unroll
      for (int f = 0; f < 4; f++) {
        fa0[f] = *frg(T1, wr + f * 16 + rl, khi);
        fa1[f] = *frg(T1, wr + f * 16 + rl, 4 + khi);
        fb0[f] = *frg(T2, wc + f * 16 + rl, khi);
        fb1[f] = *frg(T2, wc + f * 16 + rl, 4 + khi);
      }
      __builtin_amdgcn_s_setprio(1);
      #pragma unroll
      for (int fm = 0; fm < 4; fm++) {
        #pragma unroll
        for (int fn = 0; fn < 4; fn++) {
          acc[fm][fn] = __builtin_amdgcn_mfma_f32_16x16x32_bf16(fa0[fm], fb0[fn], acc[fm][fn], 0, 0, 0);
          acc[fm][fn] = __builtin_amdgcn_mfma_f32_16x16x32_bf16(fa1[fm], fb1[fn], acc[fm][fn], 0, 0, 0);
        }
      }
      __builtin_amdgcn_s_setprio(0);
    }

    __builtin_amdgcn_s_barrier();
    __builtin_amdgcn_sched_barrier(0);
    if (kt + 2 < NTl) stage(kt & 1, kt + 2);
  }

  // ---------- epilogue: fragments -> LDS fp32 -> wide coalesced stores ----------
  // BOTH modes: 1-pass [128][132]. Global-frag modes: 2-pass [64][132].
  float gma = 0.f;
  if constexpr (MODE == 3) gma = gammap[0];
  float* LDSE = (float*)smem;
  constexpr int NPASS = BOTH ? 1 : 2;

  #pragma unroll
  for (int pass = 0; pass < NPASS; ++pass) {
    if (pass) __syncthreads();
    if (BOTH || (wid >> 1) == pass) {
      #pragma unroll
      for (int fm = 0; fm < 4; fm++) {
        #pragma unroll
        for (int fn = 0; fn < 4; fn++) {
          #pragma unroll
          for (int r = 0; r < 4; r++) {
            int Lr = (BOTH ? wr : 0) + fm * 16 + ((lane >> 4) << 2) + r;
            int lc = wc + fn * 16 + rl;
            float v = acc[fm][fn][r];
            if constexpr (MODE == 0) v += bias[n0 + lc];
            if constexpr (MODE == 2) v += bias[m0 + pass * 64 + Lr];
            if constexpr (MODE == 3) v *= gma;
            LDSE[Lr * 132 + lc] = v;
          }
        }
      }
    }
    __syncthreads();

    if constexpr (MODE == 0) {
      u16* outp = (n0 < 256) ? outUa : outUb;
      long rowb = ((long)b * HW_ + m0) * 512;
      int cbu = (n0 & 255) * 2;
      #pragma unroll
      for (int k = 0; k < 8; ++k) {
        int Lr = k * 8 + (t >> 5);
        int row = pass * 64 + Lr;
        int iu  = (t & 31) * 8;
        int off = iu & 63;
        int lcol = (iu >> 6) * 32 + (off & 31);
        const float* src = &LDSE[Lr * 132 + lcol];
        u16 o[8];
        if (off < 32) {
          #pragma unroll
          for (int j = 0; j < 8; j++) o[j] = f2bf(src[j]);
        } else {
          #pragma unroll
          for (int j = 0; j < 8; j++) { float v = src[j]; u16 h = f2bf(v); o[j] = f2bf(v - bf2f(h)); }
        }
        *(short8*)(outp + rowb + (long)row * 512 + cbu + iu) = *(short8*)o;
      }
    } else if constexpr (MODE == 1) {
      float* op = dir ? outFb : outFa;
      long ob = (long)sOut * 16384;
      #pragma unroll
      for (int k = 0; k < 16; ++k) {
        int Lr = k * 8 + (t >> 5);
        int c4 = (t & 31) * 4;
        f32x4 v = *(const f32x4*)&LDSE[Lr * 132 + c4];
        *(f32x4*)(op + ob + (long)Lr * 128 + c4) = v;
      }
    } else if constexpr (MODE == 2) {
      #pragma unroll
      for (int k = 0; k < 4; ++k) {
        int Lr = k * 16 + (t >> 4);
        int row = pass * 64 + Lr;
        int c8 = (t & 15) * 8;
        const float* src = &LDSE[Lr * 132 + c8];
        u16 o[8];
        #pragma unroll
        for (int j = 0; j < 8; j++) o[j] = f2bf(src[j]);
        long addr = ((long)b * 256 + m0 + row) * HW_ + n0 + c8;
        *(short8*)(outUa + addr) = *(short8*)o;
      }
    } else {
      #pragma unroll
      for (int k = 0; k < 8; ++k) {
        int Lr = k * 16 + (t >> 4);
        int c8 = (t & 15) * 8;
        const float* src = &LDSE[Lr * 132 + c8];
        u16 o[8];
        #pragma unroll
        for (int j = 0; j < 8; j++) o[j] = f2bf(src[j]);
        long addr = ((long)b * 256 + (ct << 7) + Lr) * HW_ + (long)xx * 128 + c8;
        *(short8*)(outU + addr) = *(short8*)o;
      }
    }
  }
}

// ---------------- fused: edge -> interleaved split bf16 [p][c], mask -> plain bf16 [p][c] ----
__global__ __launch_bounds__(256) void split_transpose2(const float* __restrict__ edge,
    const float* __restrict__ mask, u16* __restrict__ Xs, u16* __restrict__ Mt)
{
  int b = blockIdx.z, c0 = blockIdx.y << 5, p0 = blockIdx.x << 5;
  __shared__ float tileE[32][33];
  __shared__ float tileM[32][33];
  int tx = threadIdx.x, ty = threadIdx.y;
  const float* E = edge + (long)b * CHW_;
  const float* M = mask + (long)b * CHW_;
  #pragma unroll
  for (int r = 0; r < 4; r++) {
    int cc = ty + (r << 3);
    long g = (long)(c0 + cc) * HW_ + p0 + tx;
    tileE[cc][tx] = E[g];
    tileM[cc][tx] = M[g];
  }
  __syncthreads();
  int blk = (c0 >> 5) * 64;
  #pragma unroll
  for (int r = 0; r < 4; r++) {
    int pp = ty + (r << 3);
    long prow = (long)b * HW_ + p0 + pp;
    float x = tileE[tx][pp];
    u16 h = f2bf(x);
    Xs[prow * 512 + blk + tx]      = h;
    Xs[prow * 512 + blk + 32 + tx] = f2bf(x - bf2f(h));
    Mt[prow * 256 + c0 + tx]       = f2bf(tileM[tx][pp]);
  }
}

// ---------------- weight prep: Wcat=[Wq;Wk] interleaved split, Wv plain, bias cat ----------
__global__ __launch_bounds__(256) void wsplit(const float* __restrict__ Wq,
    const float* __restrict__ Wk, const float* __restrict__ Wv,
    const float* __restrict__ bq, const float* __restrict__ bk,
    u16* Wc, u16* Wvp, float* bcat)
{
  int i = blockIdx.x * 256 + threadIdx.x;
  int o = i >> 8, c = i & 255;
  long pos = (long)o * 512 + (c >> 5) * 64 + (c & 31);
  float q = Wq[i]; u16 a = f2bf(q); Wc[pos] = a; Wc[pos + 32] = f2bf(q - bf2f(a));
  float k = Wk[i]; u16 d = f2bf(k);
  Wc[pos + 131072] = d; Wc[pos + 131072 + 32] = f2bf(k - bf2f(d));
  Wvp[i] = f2bf(Wv[i]);
  if (blockIdx.x == 0) {
    bcat[threadIdx.x]       = bq[threadIdx.x];
    bcat[256 + threadIdx.x] = bk[threadIdx.x];
  }
}

// ---------------- bf16 H<->W transpose: dst[bc][w*128+h] = src[bc][h*128+w] ----------------
__global__ __launch_bounds__(256) void transpose_hw_bf16(const u16* __restrict__ src,
                                                         u16* __restrict__ dst)
{
  int bc = blockIdx.z;
  int h0 = blockIdx.x << 5, w0 = blockIdx.y << 5;
  long base = (long)bc * HW_;
  __shared__ u16 tile[32][34];
  int tx = threadIdx.x, ty = threadIdx.y;
  #pragma unroll
  for (int r = 0; r < 4; r++)
    tile[ty + (r << 3)][tx] = src[base + (long)(h0 + ty + (r << 3)) * 128 + w0 + tx];
  __syncthreads();
  #pragma unroll
  for (int r = 0; r < 4; r++) {
    int ww = ty + (r << 3);
    dst[base + (long)(w0 + ww) * 128 + h0 + tx] = tile[tx][ww];
  }
}

// ---------------- softmax over concat(rowH[128], rowW[128]) + bf16 copies, vectorized ------
__global__ __launch_bounds__(256) void softmax_kernel(float* __restrict__ attH,
    float* __restrict__ attW, u16* __restrict__ aHb, u16* __restrict__ aWb)
{
  int g  = threadIdx.x & 31;                     // 32 lanes per row
  long r = (long)blockIdx.x * 8 + (threadIdx.x >> 5);
  int b = (int)(r >> 14);
  int h = (int)((r >> 7) & 127);
  int w = (int)(r & 127);
  long baseH = ((long)(b * 128 + w) * 128 + h) * 128;
  long baseW = r * 128;
  float* rp = (g < 16) ? (attH + baseH) : (attW + baseW);
  u16*   up = (g < 16) ? (aHb + baseH)  : (aWb + baseW);
  int j0 = (g & 15) * 8;
  f32x4 v0 = *(f32x4*)(rp + j0);
  f32x4 v1 = *(f32x4*)(rp + j0 + 4);
  float m = fmaxf(fmaxf(fmaxf(v0.x, v0.y), fmaxf(v0.z, v0.w)),
                  fmaxf(fmaxf(v1.x, v1.y), fmaxf(v1.z, v1.w)));
  #pragma unroll
  for (int off = 16; off; off >>= 1) m = fmaxf(m, __shfl_xor(m, off, 32));
  float e[8];
  e[0]=expf(v0.x-m); e[1]=expf(v0.y-m); e[2]=expf(v0.z-m); e[3]=expf(v0.w-m);
  e[4]=expf(v1.x-m); e[5]=expf(v1.y-m); e[6]=expf(v1.z-m); e[7]=expf(v1.w-m);
  float s = ((e[0]+e[1])+(e[2]+e[3])) + ((e[4]+e[5])+(e[6]+e[7]));
  #pragma unroll
  for (int off = 16; off; off >>= 1) s += __shfl_xor(s, off, 32);
  float inv = 1.0f / s;
  #pragma unroll
  for (int j = 0; j < 8; j++) e[j] *= inv;
  // fp32 normalized att: final output, never re-read -> nontemporal
  __builtin_nontemporal_store((f32x4){e[0], e[1], e[2], e[3]}, (f32x4*)(rp + j0));
  __builtin_nontemporal_store((f32x4){e[4], e[5], e[6], e[7]}, (f32x4*)(rp + j0 + 4));
  u16 o[8];
  #pragma unroll
  for (int j = 0; j < 8; j++) o[j] = f2bf(e[j]);
  *(short8*)(up + j0) = *(short8*)o;
}

// ---------------- merge: out = pW + tmp^T + mask ----------------
__global__ __launch_bounds__(256) void merge_kernel(const u16* __restrict__ tmp,
    const u16* __restrict__ pW, const float* __restrict__ mask, float* __restrict__ out)
{
  int bc = blockIdx.z;
  int h0 = blockIdx.x << 5, w0 = blockIdx.y << 5;
  long base = (long)bc * HW_;
  __shared__ u16 tile[32][33];
  int tx = threadIdx.x, ty = threadIdx.y;
  #pragma unroll
  for (int r = 0; r < 4; r++) {
    int ww = ty + (r << 3);
    tile[ww][tx] = tmp[base + (long)(w0 + ww) * 128 + h0 + tx];
  }
  __syncthreads();
  #pragma unroll
  for (int r = 0; r < 4; r++) {
    int hh = ty + (r << 3);
    long o = base + (long)(h0 + hh) * 128 + w0 + tx;
    float v = bf2f(pW[o]) + bf2f(tile[tx][hh]) + mask[o];
    __builtin_nontemporal_store(v, out + o);
  }
}

extern "C" void kernel_launch(void* const* d_in, const int* in_sizes, int n_in,
                              void* d_out, int out_size, void* d_ws, size_t ws_size,
                              hipStream_t stream) {
  const float* edge  = (const float*)d_in[0];
  const float* mask  = (const float*)d_in[1];
  const float* Wq    = (const float*)d_in[2];
  const float* bq    = (const float*)d_in[3];
  const float* Wk    = (const float*)d_in[4];
  const float* bk    = (const float*)d_in[5];
  const float* Wv    = (const float*)d_in[6];
  const float* bv    = (const float*)d_in[7];
  const float* gamma = (const float*)d_in[8];

  float* out  = (float*)d_out;
  float* attH = out + NT;            // B*W*H*H
  float* attW = attH + 16777216L;    // B*H*W*W

  char* W = (char*)d_ws;
  u16* Xs  = (u16*)(W);                    // 128 MiB interleaved split X [b][p][512]
  u16* Mt  = (u16*)(W + 134217728L);       // 64 MiB plain bf16 mask^T [b][p][256]
  u16* Qs  = (u16*)(W + 201326592L);       // 128 MiB
  u16* Ks  = (u16*)(W + 335544320L);       // 128 MiB
  u16* Vb  = (u16*)(W + 469762048L);       // 64 MiB
  u16* Wc  = (u16*)(W + 536870912L);       // 512 KiB Wcat interleaved
  u16* Wvp = Wc + 262144;                  // 128 KiB
  float* bcat = (float*)(Wvp + 65536);
  // reuses
  u16* Vtb = (u16*)(W);                    // over Xs (dead after proj qk)
  u16* aWb = (u16*)(W + 67108864L);        // over Xs upper half
  u16* aHb = (u16*)(W + 100663296L);
  u16* tmp = (u16*)(W + 201326592L);       // over Qs (dead after energy)
  u16* pW  = (u16*)(W + 335544320L);       // over Ks

  dim3 tb(32, 8);

  wsplit<<<256, 256, 0, stream>>>(Wq, Wk, Wv, bq, bk, Wc, Wvp, bcat);
  split_transpose2<<<dim3(512, 8, 8), tb, 0, stream>>>(edge, mask, Xs, Mt);

  gemm_nt<0><<<dim3(128, 4, 8), 256, 0, stream>>>(
      (const char*)Xs, (const char*)Wc, nullptr, nullptr, bcat, nullptr,
      nullptr, nullptr, Qs, Ks);
  gemm_nt<2><<<dim3(128, 2, 8), 256, 0, stream>>>(
      (const char*)Wvp, (const char*)Mt, nullptr, nullptr, bv, nullptr,
      nullptr, nullptr, Vb, nullptr);

  transpose_hw_bf16<<<dim3(4, 4, 2048), tb, 0, stream>>>(Vb, Vtb);

  gemm_nt<1><<<2048, 256, 0, stream>>>(
      (const char*)Qs, (const char*)Ks, nullptr, nullptr, nullptr, nullptr,
      attW, attH, nullptr, nullptr);

  softmax_kernel<<<16384, 256, 0, stream>>>(attH, attW, aHb, aWb);

  // fused av: z=0 -> H-direction (Vtb x aHb -> tmp), z=1 -> W-direction (Vb x aWb -> pW)
  gemm_nt<3><<<dim3(1024, 2, 2), 256, 0, stream>>>(
      (const char*)Vtb, (const char*)aHb, (const char*)Vb, (const char*)aWb,
      nullptr, gamma, nullptr, nullptr, tmp, pW);

  merge_kernel<<<dim3(4, 4, 2048), tb, 0, stream>>>(tmp, pW, mask, out);
}

// Round 13
// 621.775 us; speedup vs baseline: 1.8066x; 1.0792x over previous
//
#include <hip/hip_runtime.h>

typedef unsigned short u16;
typedef unsigned int   u32;
typedef __attribute__((ext_vector_type(8))) short short8;
typedef __attribute__((ext_vector_type(4))) float f32x4;

#define HW_   16384
constexpr long CHW_ = 4194304L;
constexpr long NT   = 33554432L; // B*C*H*W

#define GLDS(g, l) __builtin_amdgcn_global_load_lds( \
    (const __attribute__((address_space(1))) void*)(g), \
    (__attribute__((address_space(3))) void*)(l), 16, 0, 0)

__device__ inline u16 f2bf(float x){ u32 u = __float_as_uint(x); u += 0x7fff + ((u>>16)&1); return (u16)(u>>16); }
__device__ inline float bf2f(u16 h){ return __uint_as_float(((u32)h)<<16); }

// swizzled LDS tile: 128 rows x 8 chunks of 16B. elem(row r, chunk c) at
// u16 index r*64 + ((c ^ (r&7))<<3).
__device__ inline const short8* frg(const u16* T, int r, int c){
  return (const short8*)(T + r*64 + ((c ^ (r&7))<<3));
}

// Split layout (X/Q/K/Wcat): row = 512 u16 = 8 blocks of [32 hi | 32 lo] (1024 B).
// Plain layout (Mt/V/att/Wv): row = K-contiguous bf16.

// MODE 0: proj q+k fused (split A=Xs, B=Wcat 512 rows; interleaved split out -> Qs/Ks)
// MODE 1: energy both dirs (split A=Qs,B=Ks; fp32 out att slice; dir from blockIdx)
// MODE 2: proj v (plain A=Wv, B=Mt; bias by row; bf16 out [b][c][p])
// MODE 3: av fused H+W (plain; blockIdx.z picks (Vtb,aHb,tmp) vs (Vb,aWb,pW))
template<int MODE>
__global__ __launch_bounds__(256) void gemm_nt(
    const char* __restrict__ Aq, const char* __restrict__ Bq,
    const char* __restrict__ Aq2, const char* __restrict__ Bq2,
    const float* __restrict__ bias, const float* __restrict__ gammap,
    float* __restrict__ outFa, float* __restrict__ outFb,
    u16* __restrict__ outUa, u16* __restrict__ outUb)
{
  constexpr int NTl = (MODE <= 1) ? 8 : (MODE == 2 ? 4 : 2);
  __shared__ __align__(16) u16 smem[34048];   // 2 ring bufs of 17024 u16; epilogue fp32 [128][132]

  const int t    = threadIdx.x;
  const int lane = t & 63;
  const int wid  = t >> 6;
  const int wr   = (wid >> 1) << 6;
  const int wc   = (wid & 1) << 6;

  long abase = 0, bbase = 0, ars = 0, brs = 0;
  int b = 0, m0 = 0, n0 = 0, xx = 0, ct = 0, dir = 0, sOut = 0;
  const char* Ause = Aq;
  const char* Buse = Bq;
  u16* outU = outUa;

  if constexpr (MODE == 0) {
    b = blockIdx.z; m0 = blockIdx.x << 7; n0 = blockIdx.y << 7;
    abase = ((long)b * HW_ + m0) * 1024; ars = 1024;
    bbase = (long)n0 * 1024;             brs = 1024;
  } else if constexpr (MODE == 1) {
    int bid = blockIdx.x;
    b = bid >> 8; dir = (bid >> 7) & 1; xx = bid & 127;
    sOut = b * 128 + xx;
    if (dir) { abase = (long)b * 16777216L + (long)xx * 1024; ars = 131072; }
    else     { abase = (long)b * 16777216L + (long)xx * 131072; ars = 1024; }
    bbase = abase; brs = ars;
  } else if constexpr (MODE == 2) {
    b = blockIdx.z; m0 = blockIdx.y << 7; n0 = blockIdx.x << 7;
    abase = (long)m0 * 512;              ars = 512;
    bbase = ((long)b * HW_ + n0) * 512;  brs = 512;
  } else {
    int s = blockIdx.x; ct = blockIdx.y; b = s >> 7; xx = s & 127;
    sOut = s;
    if (blockIdx.z) { Ause = Aq2; Buse = Bq2; outU = outUb; }
    abase = ((long)b * 256 + (long)(ct << 7)) * 32768L + (long)xx * 256; ars = 32768;
    bbase = (long)s * 32768L; brs = 256;
  }

  const char* pA = Ause + abase;
  const char* pB = Buse + bbase;

  f32x4 acc[4][4];
  for (int i = 0; i < 4; i++)
    for (int j = 0; j < 4; j++)
      acc[i][j] = (f32x4){0.f, 0.f, 0.f, 0.f};

  auto stage = [&](int buf, int kt) {
    u16* T1 = smem + buf * 17024;
    u16* T2 = T1 + 8192;
    const long ko = (long)kt * 128;
    #pragma unroll
    for (int i = 0; i < 4; i++) {
      int r = (i << 5) + (t >> 3);
      int c = (t & 7) ^ (r & 7);
      GLDS(pA + (long)r * ars + ko + (c << 4), T1 + (i << 11) + ((t >> 6) << 9));
      GLDS(pB + (long)r * brs + ko + (c << 4), T2 + (i << 11) + ((t >> 6) << 9));
    }
  };

  const int khi = lane >> 4;
  const int rl  = lane & 15;

  stage(0, 0);
  stage(1, 1);

  #pragma unroll
  for (int kt = 0; kt < NTl; ++kt) {
    if (kt + 1 < NTl) asm volatile("s_waitcnt vmcnt(8)" ::: "memory");
    else              asm volatile("s_waitcnt vmcnt(0)" ::: "memory");
    __builtin_amdgcn_sched_barrier(0);
    __builtin_amdgcn_s_barrier();
    __builtin_amdgcn_sched_barrier(0);

    const u16* T1 = smem + (kt & 1) * 17024;
    const u16* T2 = T1 + 8192;

    short8 fa0[4], fa1[4], fb0[4], fb1[4];
    #pragma unroll
    for (int f = 0; f < 4; f++) {
      fa0[f] = *frg(T1, wr + f * 16 + rl, khi);
      fa1[f] = *frg(T1, wr + f * 16 + rl, 4 + khi);
      fb0[f] = *frg(T2, wc + f * 16 + rl, khi);
      fb1[f] = *frg(T2, wc + f * 16 + rl, 4 + khi);
    }

    __builtin_amdgcn_s_setprio(1);
    #pragma unroll
    for (int fm = 0; fm < 4; fm++) {
      #pragma unroll
      for (int fn = 0; fn < 4; fn++) {
        if constexpr (MODE <= 1) {
          // split: hi*hi + hi*lo + lo*hi
          acc[fm][fn] = __builtin_amdgcn_mfma_f32_16x16x32_bf16(fa0[fm], fb0[fn], acc[fm][fn], 0, 0, 0);
          acc[fm][fn] = __builtin_amdgcn_mfma_f32_16x16x32_bf16(fa0[fm], fb1[fn], acc[fm][fn], 0, 0, 0);
          acc[fm][fn] = __builtin_amdgcn_mfma_f32_16x16x32_bf16(fa1[fm], fb0[fn], acc[fm][fn], 0, 0, 0);
        } else {
          // plain BK=64: two k-halves
          acc[fm][fn] = __builtin_amdgcn_mfma_f32_16x16x32_bf16(fa0[fm], fb0[fn], acc[fm][fn], 0, 0, 0);
          acc[fm][fn] = __builtin_amdgcn_mfma_f32_16x16x32_bf16(fa1[fm], fb1[fn], acc[fm][fn], 0, 0, 0);
        }
      }
    }
    __builtin_amdgcn_s_setprio(0);

    __builtin_amdgcn_s_barrier();
    __builtin_amdgcn_sched_barrier(0);
    if (kt + 2 < NTl) stage(kt & 1, kt + 2);
  }

  // ---------- epilogue: fragments -> LDS fp32 [128][132] -> wide coalesced stores ----------
  float gma = 0.f;
  if constexpr (MODE == 3) gma = gammap[0];
  float* LDSE = (float*)smem;

  #pragma unroll
  for (int fm = 0; fm < 4; fm++) {
    #pragma unroll
    for (int fn = 0; fn < 4; fn++) {
      #pragma unroll
      for (int r = 0; r < 4; r++) {
        int lr = wr + fm * 16 + ((lane >> 4) << 2) + r;
        int lc = wc + fn * 16 + rl;
        float v = acc[fm][fn][r];
        if constexpr (MODE == 0) v += bias[n0 + lc];
        if constexpr (MODE == 2) v += bias[m0 + lr];
        if constexpr (MODE == 3) v *= gma;
        LDSE[lr * 132 + lc] = v;
      }
    }
  }
  __syncthreads();

  if constexpr (MODE == 0) {
    u16* outp = (n0 < 256) ? outUa : outUb;
    long rowb = ((long)b * HW_ + m0) * 512;   // u16 units, row = 512 u16
    int cbu = (n0 & 255) * 2;                  // u16 offset of this 128-col half
    #pragma unroll
    for (int k = 0; k < 16; ++k) {
      int row = k * 8 + (t >> 5);
      int iu  = (t & 31) * 8;                  // u16 offset within 256-u16 piece
      int off = iu & 63;
      int lcol = (iu >> 6) * 32 + (off & 31);
      const float* src = &LDSE[row * 132 + lcol];
      u16 o[8];
      if (off < 32) {
        #pragma unroll
        for (int j = 0; j < 8; j++) o[j] = f2bf(src[j]);
      } else {
        #pragma unroll
        for (int j = 0; j < 8; j++) { float v = src[j]; u16 h = f2bf(v); o[j] = f2bf(v - bf2f(h)); }
      }
      *(short8*)(outp + rowb + (long)row * 512 + cbu + iu) = *(short8*)o;
    }
  } else if constexpr (MODE == 1) {
    float* op = dir ? outFb : outFa;
    long ob = (long)sOut * 16384;
    #pragma unroll
    for (int k = 0; k < 16; ++k) {
      int row = k * 8 + (t >> 5);
      int c4 = (t & 31) * 4;
      f32x4 v = *(const f32x4*)&LDSE[row * 132 + c4];
      *(f32x4*)(op + ob + (long)row * 128 + c4) = v;
    }
  } else {
    #pragma unroll
    for (int k = 0; k < 8; ++k) {
      int row = k * 16 + (t >> 4);
      int c8 = (t & 15) * 8;
      const float* src = &LDSE[row * 132 + c8];
      u16 o[8];
      #pragma unroll
      for (int j = 0; j < 8; j++) o[j] = f2bf(src[j]);
      long addr;
      if constexpr (MODE == 2) addr = ((long)b * 256 + m0 + row) * HW_ + n0 + c8;
      else                     addr = ((long)b * 256 + (ct << 7) + row) * HW_ + (long)xx * 128 + c8;
      *(short8*)(outU + addr) = *(short8*)o;
    }
  }
}

// ---------------- fused: edge -> interleaved split bf16 [p][c], mask -> plain bf16 [p][c] ----
__global__ __launch_bounds__(256) void split_transpose2(const float* __restrict__ edge,
    const float* __restrict__ mask, u16* __restrict__ Xs, u16* __restrict__ Mt)
{
  int b = blockIdx.z, c0 = blockIdx.y << 5, p0 = blockIdx.x << 5;
  __shared__ float tileE[32][33];
  __shared__ float tileM[32][33];
  int tx = threadIdx.x, ty = threadIdx.y;
  const float* E = edge + (long)b * CHW_;
  const float* M = mask + (long)b * CHW_;
  #pragma unroll
  for (int r = 0; r < 4; r++) {
    int cc = ty + (r << 3);
    long g = (long)(c0 + cc) * HW_ + p0 + tx;
    tileE[cc][tx] = E[g];
    tileM[cc][tx] = M[g];
  }
  __syncthreads();
  int blk = (c0 >> 5) * 64;
  #pragma unroll
  for (int r = 0; r < 4; r++) {
    int pp = ty + (r << 3);
    long prow = (long)b * HW_ + p0 + pp;
    float x = tileE[tx][pp];
    u16 h = f2bf(x);
    Xs[prow * 512 + blk + tx]      = h;
    Xs[prow * 512 + blk + 32 + tx] = f2bf(x - bf2f(h));
    Mt[prow * 256 + c0 + tx]       = f2bf(tileM[tx][pp]);
  }
}

// ---------------- weight prep: Wcat=[Wq;Wk] interleaved split, Wv plain, bias cat ----------
__global__ __launch_bounds__(256) void wsplit(const float* __restrict__ Wq,
    const float* __restrict__ Wk, const float* __restrict__ Wv,
    const float* __restrict__ bq, const float* __restrict__ bk,
    u16* Wc, u16* Wvp, float* bcat)
{
  int i = blockIdx.x * 256 + threadIdx.x;
  int o = i >> 8, c = i & 255;
  long pos = (long)o * 512 + (c >> 5) * 64 + (c & 31);
  float q = Wq[i]; u16 a = f2bf(q); Wc[pos] = a; Wc[pos + 32] = f2bf(q - bf2f(a));
  float k = Wk[i]; u16 d = f2bf(k);
  Wc[pos + 131072] = d; Wc[pos + 131072 + 32] = f2bf(k - bf2f(d));
  Wvp[i] = f2bf(Wv[i]);
  if (blockIdx.x == 0) {
    bcat[threadIdx.x]       = bq[threadIdx.x];
    bcat[256 + threadIdx.x] = bk[threadIdx.x];
  }
}

// ---------------- bf16 H<->W transpose: dst[bc][w*128+h] = src[bc][h*128+w] ----------------
__global__ __launch_bounds__(256) void transpose_hw_bf16(const u16* __restrict__ src,
                                                         u16* __restrict__ dst)
{
  int bc = blockIdx.z;
  int h0 = blockIdx.x << 5, w0 = blockIdx.y << 5;
  long base = (long)bc * HW_;
  __shared__ u16 tile[32][34];
  int tx = threadIdx.x, ty = threadIdx.y;
  #pragma unroll
  for (int r = 0; r < 4; r++)
    tile[ty + (r << 3)][tx] = src[base + (long)(h0 + ty + (r << 3)) * 128 + w0 + tx];
  __syncthreads();
  #pragma unroll
  for (int r = 0; r < 4; r++) {
    int ww = ty + (r << 3);
    dst[base + (long)(w0 + ww) * 128 + h0 + tx] = tile[tx][ww];
  }
}

// ---------------- softmax over concat(rowH[128], rowW[128]) + bf16 copies, vectorized ------
__global__ __launch_bounds__(256) void softmax_kernel(float* __restrict__ attH,
    float* __restrict__ attW, u16* __restrict__ aHb, u16* __restrict__ aWb)
{
  int g  = threadIdx.x & 31;                     // 32 lanes per row
  long r = (long)blockIdx.x * 8 + (threadIdx.x >> 5);
  int b = (int)(r >> 14);
  int h = (int)((r >> 7) & 127);
  int w = (int)(r & 127);
  long baseH = ((long)(b * 128 + w) * 128 + h) * 128;
  long baseW = r * 128;
  float* rp = (g < 16) ? (attH + baseH) : (attW + baseW);
  u16*   up = (g < 16) ? (aHb + baseH)  : (aWb + baseW);
  int j0 = (g & 15) * 8;
  f32x4 v0 = *(f32x4*)(rp + j0);
  f32x4 v1 = *(f32x4*)(rp + j0 + 4);
  float m = fmaxf(fmaxf(fmaxf(v0.x, v0.y), fmaxf(v0.z, v0.w)),
                  fmaxf(fmaxf(v1.x, v1.y), fmaxf(v1.z, v1.w)));
  #pragma unroll
  for (int off = 16; off; off >>= 1) m = fmaxf(m, __shfl_xor(m, off, 32));
  float e[8];
  e[0]=expf(v0.x-m); e[1]=expf(v0.y-m); e[2]=expf(v0.z-m); e[3]=expf(v0.w-m);
  e[4]=expf(v1.x-m); e[5]=expf(v1.y-m); e[6]=expf(v1.z-m); e[7]=expf(v1.w-m);
  float s = ((e[0]+e[1])+(e[2]+e[3])) + ((e[4]+e[5])+(e[6]+e[7]));
  #pragma unroll
  for (int off = 16; off; off >>= 1) s += __shfl_xor(s, off, 32);
  float inv = 1.0f / s;
  #pragma unroll
  for (int j = 0; j < 8; j++) e[j] *= inv;
  // fp32 normalized att: final output, never re-read -> nontemporal
  __builtin_nontemporal_store((f32x4){e[0], e[1], e[2], e[3]}, (f32x4*)(rp + j0));
  __builtin_nontemporal_store((f32x4){e[4], e[5], e[6], e[7]}, (f32x4*)(rp + j0 + 4));
  u16 o[8];
  #pragma unroll
  for (int j = 0; j < 8; j++) o[j] = f2bf(e[j]);
  *(short8*)(up + j0) = *(short8*)o;
}

// ---------------- merge: out = pW + tmp^T + mask ----------------
__global__ __launch_bounds__(256) void merge_kernel(const u16* __restrict__ tmp,
    const u16* __restrict__ pW, const float* __restrict__ mask, float* __restrict__ out)
{
  int bc = blockIdx.z;
  int h0 = blockIdx.x << 5, w0 = blockIdx.y << 5;
  long base = (long)bc * HW_;
  __shared__ u16 tile[32][33];
  int tx = threadIdx.x, ty = threadIdx.y;
  #pragma unroll
  for (int r = 0; r < 4; r++) {
    int ww = ty + (r << 3);
    tile[ww][tx] = tmp[base + (long)(w0 + ww) * 128 + h0 + tx];
  }
  __syncthreads();
  #pragma unroll
  for (int r = 0; r < 4; r++) {
    int hh = ty + (r << 3);
    long o = base + (long)(h0 + hh) * 128 + w0 + tx;
    float v = bf2f(pW[o]) + bf2f(tile[tx][hh]) + mask[o];
    __builtin_nontemporal_store(v, out + o);
  }
}

extern "C" void kernel_launch(void* const* d_in, const int* in_sizes, int n_in,
                              void* d_out, int out_size, void* d_ws, size_t ws_size,
                              hipStream_t stream) {
  const float* edge  = (const float*)d_in[0];
  const float* mask  = (const float*)d_in[1];
  const float* Wq    = (const float*)d_in[2];
  const float* bq    = (const float*)d_in[3];
  const float* Wk    = (const float*)d_in[4];
  const float* bk    = (const float*)d_in[5];
  const float* Wv    = (const float*)d_in[6];
  const float* bv    = (const float*)d_in[7];
  const float* gamma = (const float*)d_in[8];

  float* out  = (float*)d_out;
  float* attH = out + NT;            // B*W*H*H
  float* attW = attH + 16777216L;    // B*H*W*W

  char* W = (char*)d_ws;
  u16* Xs  = (u16*)(W);                    // 128 MiB interleaved split X [b][p][512]
  u16* Mt  = (u16*)(W + 134217728L);       // 64 MiB plain bf16 mask^T [b][p][256]
  u16* Qs  = (u16*)(W + 201326592L);       // 128 MiB
  u16* Ks  = (u16*)(W + 335544320L);       // 128 MiB
  u16* Vb  = (u16*)(W + 469762048L);       // 64 MiB
  u16* Wc  = (u16*)(W + 536870912L);       // 512 KiB Wcat interleaved
  u16* Wvp = Wc + 262144;                  // 128 KiB
  float* bcat = (float*)(Wvp + 65536);
  // reuses
  u16* Vtb = (u16*)(W);                    // over Xs (dead after proj qk)
  u16* aWb = (u16*)(W + 67108864L);        // over Xs upper half
  u16* aHb = (u16*)(W + 100663296L);
  u16* tmp = (u16*)(W + 201326592L);       // over Qs (dead after energy)
  u16* pW  = (u16*)(W + 335544320L);       // over Ks

  dim3 tb(32, 8);

  wsplit<<<256, 256, 0, stream>>>(Wq, Wk, Wv, bq, bk, Wc, Wvp, bcat);
  split_transpose2<<<dim3(512, 8, 8), tb, 0, stream>>>(edge, mask, Xs, Mt);

  gemm_nt<0><<<dim3(128, 4, 8), 256, 0, stream>>>(
      (const char*)Xs, (const char*)Wc, nullptr, nullptr, bcat, nullptr,
      nullptr, nullptr, Qs, Ks);
  gemm_nt<2><<<dim3(128, 2, 8), 256, 0, stream>>>(
      (const char*)Wvp, (const char*)Mt, nullptr, nullptr, bv, nullptr,
      nullptr, nullptr, Vb, nullptr);

  transpose_hw_bf16<<<dim3(4, 4, 2048), tb, 0, stream>>>(Vb, Vtb);

  gemm_nt<1><<<2048, 256, 0, stream>>>(
      (const char*)Qs, (const char*)Ks, nullptr, nullptr, nullptr, nullptr,
      attW, attH, nullptr, nullptr);

  softmax_kernel<<<16384, 256, 0, stream>>>(attH, attW, aHb, aWb);

  // fused av: z=0 -> H-direction (Vtb x aHb -> tmp), z=1 -> W-direction (Vb x aWb -> pW)
  gemm_nt<3><<<dim3(1024, 2, 2), 256, 0, stream>>>(
      (const char*)Vtb, (const char*)aHb, (const char*)Vb, (const char*)aWb,
      nullptr, gamma, nullptr, nullptr, tmp, pW);

  merge_kernel<<<dim3(4, 4, 2048), tb, 0, stream>>>(tmp, pW, mask, out);
}